// Round 9
// baseline (234.912 us; speedup 1.0000x reference)
//
#include <hip/hip_runtime.h>
#include <hip/hip_fp16.h>

typedef _Float16 half8_t __attribute__((ext_vector_type(8)));
typedef float float4_t __attribute__((ext_vector_type(4)));

__device__ __forceinline__ float2 h2f2(unsigned int u) {
  return __half22float2(__builtin_bit_cast(__half2, u));
}
__device__ __forceinline__ unsigned int f2h2(float a, float b) {
  return __builtin_bit_cast(unsigned int, __floats2half2_rn(a, b));
}

#if __has_builtin(__builtin_amdgcn_fdot2)
typedef _Float16 h2v __attribute__((ext_vector_type(2)));
__device__ __forceinline__ float fdot2(unsigned int a, unsigned int b, float c) {
  return __builtin_amdgcn_fdot2(__builtin_bit_cast(h2v, a),
                                __builtin_bit_cast(h2v, b), c, false);
}
#else
__device__ __forceinline__ float fdot2(unsigned int a, unsigned int b, float c) {
  float2 fa = h2f2(a), fb = h2f2(b);
  return fmaf(fa.y, fb.y, fmaf(fa.x, fb.x, c));
}
#endif

// ---------------- K0: LayerNorm stats per (bb, pixel-pair) ----------------
// stats4[bb*8192 + jp] = (mu0, rsig0, mu1, rsig1) for px pair jp of frame bb.
__global__ __launch_bounds__(256) void k_stats(const float2* __restrict__ x2,
                                               float4* __restrict__ stats4) {
  int id = blockIdx.x * 256 + threadIdx.x;   // 32 * 8192
  int bb = id >> 13;
  int jp = id & 8191;
  const float2* xp = x2 + ((size_t)bb << 19) + jp;
  float s0 = 0.f, q0 = 0.f, s1 = 0.f, q1 = 0.f;
#pragma unroll
  for (int ci = 0; ci < 64; ++ci) {
    float2 v = xp[(size_t)ci << 13];
    s0 += v.x; q0 = fmaf(v.x, v.x, q0);
    s1 += v.y; q1 = fmaf(v.y, v.y, q1);
  }
  float mu0 = s0 * (1.f / 64.f), mu1 = s1 * (1.f / 64.f);
  float4 r;
  r.x = mu0; r.y = rsqrtf(fmaf(-mu0, mu0, q0 * (1.f / 64.f)) + 1e-5f);
  r.z = mu1; r.w = rsqrtf(fmaf(-mu1, mu1, q1 * (1.f / 64.f)) + 1e-5f);
  stats4[id] = r;
}

// ---------------- K0b: pack all weights to half2 ----------------
__global__ __launch_bounds__(256) void k_wpack(
    const float* __restrict__ qkvw, const float* __restrict__ dww,
    const float* __restrict__ projw, unsigned int* __restrict__ qkvpk,
    unsigned int* __restrict__ dwpk, unsigned int* __restrict__ projpk) {
  int t = blockIdx.x * 256 + threadIdx.x;
  if (t < 2048) {
    int o = t >> 5, c2 = t & 31;
    projpk[t] = f2h2(projw[(o << 6) + 2 * c2], projw[(o << 6) + 2 * c2 + 1]);
  } else if (t < 2432) {
    int i = t - 2048;
    int ch = i >> 3, tp = i & 7;
    qkvpk[i] = f2h2(qkvw[(ch << 4) + 2 * tp], qkvw[(ch << 4) + 2 * tp + 1]);
  } else if (t < 2648) {
    int i = t - 2432;
    int pl = i / 9, k = i - pl * 9;
    dwpk[i] = f2h2(dww[18 * pl + k], dww[18 * pl + 9 + k]);
  }
}

// ---------------- K1: LN -> xn fp16, t-innermost -------------------------
// xn word layout: [bc][px][8 words], word tp = halves (t=2tp, t=2tp+1).
__global__ __launch_bounds__(256) void k_xn(
    const float2* __restrict__ x2, const float4* __restrict__ stats4,
    const float* __restrict__ lnw, const float* __restrict__ lnb,
    unsigned int* __restrict__ xnw) {
  int bc = blockIdx.y, bt = bc >> 6, ci = bc & 63;
  int jp = blockIdx.x * 256 + threadIdx.x;   // px-pair [0,8192)
  float lw = lnw[ci], lb = lnb[ci];
  unsigned int w0[8], w1[8];
#pragma unroll
  for (int tp = 0; tp < 8; ++tp) {
    int bb0 = (bt << 4) + 2 * tp;
    float2 xa = x2[(((size_t)((bb0 << 6) + ci)) << 13) + jp];
    float2 xb = x2[(((size_t)(((bb0 + 1) << 6) + ci)) << 13) + jp];
    float4 sa = stats4[((size_t)bb0 << 13) + jp];
    float4 sb = stats4[((size_t)(bb0 + 1) << 13) + jp];
    w0[tp] = f2h2(fmaf((xa.x - sa.x) * sa.y, lw, lb),
                  fmaf((xb.x - sb.x) * sb.y, lw, lb));
    w1[tp] = f2h2(fmaf((xa.y - sa.z) * sa.w, lw, lb),
                  fmaf((xb.y - sb.z) * sb.w, lw, lb));
  }
  size_t base = (((size_t)bc << 14) + 2 * (size_t)jp) * 8;
  *reinterpret_cast<uint4*>(&xnw[base + 0]) = make_uint4(w0[0], w0[1], w0[2], w0[3]);
  *reinterpret_cast<uint4*>(&xnw[base + 4]) = make_uint4(w0[4], w0[5], w0[6], w0[7]);
  *reinterpret_cast<uint4*>(&xnw[base + 8]) = make_uint4(w1[0], w1[1], w1[2], w1[3]);
  *reinterpret_cast<uint4*>(&xnw[base + 12]) = make_uint4(w1[4], w1[5], w1[6], w1[7]);
}

// ---------------- K2: MFMA 1x1 + dw3x3 + attn partials + v ---------------
// grid (32 tiles of 32x16, 128 = bt*64+ci), block 256.
// Chunks m=0,1: heads 2m,2m+1 (q ch 8m..8m+7, k ch 16+8m..); m=2: v ch 32..47.
__global__ __launch_bounds__(256) void k_fused(
    const unsigned int* __restrict__ xnw, const unsigned int* __restrict__ qkvpk,
    const unsigned int* __restrict__ dwpk, unsigned int* __restrict__ vbuf,
    float* __restrict__ Sacc, float* __restrict__ Nacc) {
  __shared__ unsigned int pre[8 * 612];   // 8 ch-pair planes x halo px
  __shared__ unsigned int qk[16 * 258];   // 16 ch rows x 256 px-pair words
  int tid = threadIdx.x;
  int bc = blockIdx.y;
  int tx0 = (blockIdx.x & 3) << 5, ty0 = (blockIdx.x >> 2) << 4;
  int lane15 = tid & 15;
  int kg = (tid >> 4) & 3;    // MFMA k-block / D row-group
  int wv = tid >> 6;
  int iy = tid >> 4, jx = tid & 15;
  int dwbase = iy * 34 + 2 * jx;
  size_t xnbase = (size_t)bc << 17;   // bc*16384*8 words

  for (int m = 0; m < 3; ++m) {
    // ---- S/N partials for previous chunk (reads qk) ----
    if (m > 0) {
      int pm = m - 1;
      {
        int combo = tid >> 3, pc = tid & 7;
        int hp_ = combo >> 4, cd = combo & 15, cc = cd >> 2, dd = cd & 3;
        const unsigned int* qrow = qk + (4 * hp_ + cc) * 258;
        const unsigned int* krow = qk + (8 + 4 * hp_ + dd) * 258;
        float s = 0.f;
#pragma unroll
        for (int i = 0; i < 16; ++i) {
          uint2 q2 = *reinterpret_cast<const uint2*>(&qrow[2 * pc + (i << 4)]);
          uint2 k2 = *reinterpret_cast<const uint2*>(&krow[2 * pc + (i << 4)]);
          s = fdot2(q2.x, k2.x, s);
          s = fdot2(q2.y, k2.y, s);
        }
        s += __shfl_xor(s, 1); s += __shfl_xor(s, 2); s += __shfl_xor(s, 4);
        if (pc == 0)
          atomicAdd(&Sacc[((bc << 2) + 2 * pm + hp_) * 16 + cc * 4 + dd], s);
      }
      {
        int row = tid >> 4, pc = tid & 15;
        const unsigned int* rp = qk + row * 258;
        float n = 0.f;
#pragma unroll
        for (int i = 0; i < 8; ++i) {
          uint2 v2 = *reinterpret_cast<const uint2*>(&rp[2 * pc + (i << 5)]);
          n = fdot2(v2.x, v2.x, n);
          n = fdot2(v2.y, v2.y, n);
        }
        n += __shfl_xor(n, 1); n += __shfl_xor(n, 2);
        n += __shfl_xor(n, 4); n += __shfl_xor(n, 8);
        if (pc == 0) {
          int gidx = (row < 8) ? (8 * pm + row) : (16 + 8 * pm + (row - 8));
          atomicAdd(&Nacc[(bc << 5) + gidx], n);
        }
      }
    }
    // ---- MFMA 1x1: pre[16 local ch][612 halo px], K=16 zero-padded to 32 --
    {
      int gch = (m < 2)
                    ? ((lane15 < 8) ? (8 * m + lane15) : (16 + 8 * m + (lane15 - 8)))
                    : (32 + lane15);
      uint4 aw = make_uint4(0, 0, 0, 0);
      if (kg < 2) aw = *reinterpret_cast<const uint4*>(&qkvpk[gch * 8 + 4 * kg]);
      half8_t af = __builtin_bit_cast(half8_t, aw);
      float4_t zz = {0.f, 0.f, 0.f, 0.f};
      for (int T = wv; T < 39; T += 4) {
        int hp = T * 16 + lane15;
        int hy = hp / 34, hx = hp - hy * 34;
        int gy = ty0 + hy - 1, gx = tx0 + hx - 1;
        bool inb = (hp < 612) && ((unsigned)gy < 128u) && ((unsigned)gx < 128u);
        uint4 bw = make_uint4(0, 0, 0, 0);
        if (inb && kg < 2)
          bw = *reinterpret_cast<const uint4*>(
              &xnw[xnbase + (size_t)((gy << 7) + gx) * 8 + 4 * kg]);
        half8_t bf = __builtin_bit_cast(half8_t, bw);
        float4_t d = __builtin_amdgcn_mfma_f32_16x16x32_f16(af, bf, zz, 0, 0, 0);
        if (hp < 612) {
          pre[(2 * kg) * 612 + hp] = f2h2(d[0], d[1]);
          pre[(2 * kg + 1) * 612 + hp] = f2h2(d[2], d[3]);
        }
      }
    }
    __syncthreads();
    // ---- dw 3x3 (packed fp16) ----
#pragma unroll
    for (int pl = 0; pl < 8; ++pl) {
      int gpl = (m < 2) ? ((pl < 4) ? (4 * m + pl) : (8 + 4 * m + (pl - 4)))
                        : (16 + pl);
      const unsigned int* wp = dwpk + gpl * 9;
      __half2 a0 = __floats2half2_rn(0.f, 0.f), a1 = a0;
      int base = pl * 612 + dwbase;
#pragma unroll
      for (int dy = 0; dy < 3; ++dy) {
        uint2 A = *reinterpret_cast<const uint2*>(&pre[base + dy * 34]);
        uint2 B = *reinterpret_cast<const uint2*>(&pre[base + dy * 34 + 2]);
        __half2 d0 = __builtin_bit_cast(__half2, A.x);
        __half2 d1 = __builtin_bit_cast(__half2, A.y);
        __half2 d2 = __builtin_bit_cast(__half2, B.x);
        __half2 d3 = __builtin_bit_cast(__half2, B.y);
        __half2 w0 = __builtin_bit_cast(__half2, wp[dy * 3 + 0]);
        __half2 w1 = __builtin_bit_cast(__half2, wp[dy * 3 + 1]);
        __half2 w2 = __builtin_bit_cast(__half2, wp[dy * 3 + 2]);
        a0 = __hfma2(w0, d0, a0); a0 = __hfma2(w1, d1, a0); a0 = __hfma2(w2, d2, a0);
        a1 = __hfma2(w0, d1, a1); a1 = __hfma2(w1, d2, a1); a1 = __hfma2(w2, d3, a1);
      }
      unsigned int u0 = __builtin_bit_cast(unsigned int, a0);
      unsigned int u1 = __builtin_bit_cast(unsigned int, a1);
      if (m < 2) {
        qk[(2 * pl) * 258 + tid]     = (u0 & 0xFFFFu) | (u1 << 16);      // chE
        qk[(2 * pl + 1) * 258 + tid] = (u0 >> 16) | (u1 & 0xFFFF0000u);  // chO
      } else {
        uint2 st2;
        st2.x = u0;   // (chE,chO)@px0
        st2.y = u1;   // @px1
        size_t idx = ((size_t)(bc * 8 + pl) << 14) +
                     (size_t)((ty0 + iy) << 7) + tx0 + 2 * jx;
        *reinterpret_cast<uint2*>(vbuf + idx) = st2;
      }
    }
    if (m < 2) __syncthreads();
  }
}

// ---------------- K3: softmax -> packed fp16 attention rows ----------------
__global__ __launch_bounds__(256) void k_softmax(
    const float* __restrict__ Sacc, const float* __restrict__ Nacc,
    const float* __restrict__ temp, unsigned int* __restrict__ attnpk) {
  int idx = blockIdx.x * 256 + threadIdx.x;
  if (idx >= 512) return;
  int b = idx >> 2, hd = idx & 3;   // b = bt*64 + ci
  int bt = b >> 6, ci = b & 63;
  float tp = temp[hd];
  float iq[4], ik[4];
#pragma unroll
  for (int c = 0; c < 4; ++c) {
    iq[c] = 1.f / fmaxf(sqrtf(Nacc[(b << 5) + (hd << 2) + c]), 1e-12f);
    ik[c] = 1.f / fmaxf(sqrtf(Nacc[(b << 5) + 16 + (hd << 2) + c]), 1e-12f);
  }
  const float* Sp = Sacc + ((b << 2) + hd) * 16;
#pragma unroll
  for (int c = 0; c < 4; ++c) {
    float l[4];
#pragma unroll
    for (int d = 0; d < 4; ++d) l[d] = Sp[c * 4 + d] * iq[c] * ik[d] * tp;
    float m = fmaxf(fmaxf(l[0], l[1]), fmaxf(l[2], l[3]));
    float e0 = expf(l[0] - m), e1 = expf(l[1] - m);
    float e2 = expf(l[2] - m), e3 = expf(l[3] - m);
    float inv = 1.f / (e0 + e1 + e2 + e3);
    unsigned int* dst = attnpk + ((((bt * 4 + hd) * 4 + c) << 7) + ci * 2);
    dst[0] = f2h2(e0 * inv, e1 * inv);
    dst[1] = f2h2(e2 * inv, e3 * inv);
  }
}

// ---------------- K4: out = proj @ (attn . v), 2 px/thread ----------------
__global__ __launch_bounds__(256) void k_outproj(
    const unsigned int* __restrict__ vbuf, const unsigned int* __restrict__ attnpk,
    const unsigned int* __restrict__ projpk, float* __restrict__ out) {
  int comb = blockIdx.y;
  int bt = comb >> 4, hd = (comb >> 2) & 3, c = comb & 3;
  int px = ((blockIdx.x << 8) + threadIdx.x) << 1;

  const unsigned int* apk = attnpk + (((bt * 4 + hd) * 4 + c) << 7);  // uniform
  float accA[64], accB[64];
#pragma unroll
  for (int o = 0; o < 64; ++o) { accA[o] = 0.f; accB[o] = 0.f; }

  size_t vbase = ((((size_t)bt * 512) + hd * 2) << 14) + px;
  for (int ci2 = 0; ci2 < 32; ++ci2) {
    size_t off0 = vbase + (((size_t)(2 * ci2) * 8) << 14);
    size_t off1 = off0 + ((size_t)8 << 14);
    uint2 v0a = *reinterpret_cast<const uint2*>(&vbuf[off0]);
    uint2 v0b = *reinterpret_cast<const uint2*>(&vbuf[off0 + (1 << 14)]);
    uint2 v1a = *reinterpret_cast<const uint2*>(&vbuf[off1]);
    uint2 v1b = *reinterpret_cast<const uint2*>(&vbuf[off1 + (1 << 14)]);
    float y0A = fdot2(v0a.x, apk[4 * ci2 + 0], fdot2(v0b.x, apk[4 * ci2 + 1], 0.f));
    float y0B = fdot2(v0a.y, apk[4 * ci2 + 0], fdot2(v0b.y, apk[4 * ci2 + 1], 0.f));
    float y1A = fdot2(v1a.x, apk[4 * ci2 + 2], fdot2(v1b.x, apk[4 * ci2 + 3], 0.f));
    float y1B = fdot2(v1a.y, apk[4 * ci2 + 2], fdot2(v1b.y, apk[4 * ci2 + 3], 0.f));
    unsigned int y2A = f2h2(y0A, y1A);
    unsigned int y2B = f2h2(y0B, y1B);
#pragma unroll
    for (int o = 0; o < 64; ++o) {
      unsigned int w = projpk[(o << 5) + ci2];
      accA[o] = fdot2(y2A, w, accA[o]);
      accB[o] = fdot2(y2B, w, accB[o]);
    }
  }
  float* op = out + (((size_t)comb << 6) << 14) + px;
#pragma unroll
  for (int o = 0; o < 64; ++o)
    *reinterpret_cast<float2*>(&op[(size_t)o << 14]) = make_float2(accA[o], accB[o]);
}

extern "C" void kernel_launch(void* const* d_in, const int* in_sizes, int n_in,
                              void* d_out, int out_size, void* d_ws, size_t ws_size,
                              hipStream_t stream) {
  const float* x = (const float*)d_in[0];
  const float* lnw = (const float*)d_in[1];
  const float* lnb = (const float*)d_in[2];
  const float* qkvw = (const float*)d_in[3];
  const float* dww = (const float*)d_in[4];
  const float* projw = (const float*)d_in[5];
  const float* temp = (const float*)d_in[6];
  float* out = (float*)d_out;

  // workspace: xn 64 MiB | vbuf 64 MiB | stats 4 MiB | Sacc | Nacc | attnpk |
  //            projpk | qkvpk | dwpk  (~132.1 MiB, <= proven round-2 usage)
  unsigned int* xnw = (unsigned int*)d_ws;
  unsigned int* vbuf = xnw + (67108864ull / 4);
  char* tail = (char*)d_ws + 134217728ull;
  float4* stats4 = (float4*)tail;                         // 4 MiB
  float* Sacc = (float*)(tail + 4194304ull);              // 8192 f32
  float* Nacc = Sacc + 8192;                              // 4096 f32
  unsigned int* attnpk = (unsigned int*)(Nacc + 4096);    // 4096 u32
  unsigned int* projpk = attnpk + 4096;                   // 2048 u32
  unsigned int* qkvpk = projpk + 2048;                    // 384 u32
  unsigned int* dwpk = qkvpk + 384;                       // 216 u32

  hipMemsetAsync(Sacc, 0, (8192 + 4096) * sizeof(float), stream);
  k_stats<<<dim3(1024), dim3(256), 0, stream>>>((const float2*)x, stats4);
  k_wpack<<<dim3(11), dim3(256), 0, stream>>>(qkvw, dww, projw, qkvpk, dwpk, projpk);
  k_xn<<<dim3(32, 128), dim3(256), 0, stream>>>((const float2*)x, stats4, lnw, lnb, xnw);
  k_fused<<<dim3(32, 128), dim3(256), 0, stream>>>(xnw, qkvpk, dwpk, vbuf, Sacc, Nacc);
  k_softmax<<<dim3(2), dim3(256), 0, stream>>>(Sacc, Nacc, temp, attnpk);
  k_outproj<<<dim3(32, 32), dim3(256), 0, stream>>>(vbuf, attnpk, projpk, out);
}

// Round 10
// 214.893 us; speedup vs baseline: 1.0932x; 1.0932x over previous
//
#include <hip/hip_runtime.h>
#include <hip/hip_fp16.h>

typedef _Float16 half8_t __attribute__((ext_vector_type(8)));
typedef float float4_t __attribute__((ext_vector_type(4)));

__device__ __forceinline__ float2 h2f2(unsigned int u) {
  return __half22float2(__builtin_bit_cast(__half2, u));
}
__device__ __forceinline__ unsigned int f2h2(float a, float b) {
  return __builtin_bit_cast(unsigned int, __floats2half2_rn(a, b));
}

#if __has_builtin(__builtin_amdgcn_fdot2)
typedef _Float16 h2v __attribute__((ext_vector_type(2)));
__device__ __forceinline__ float fdot2(unsigned int a, unsigned int b, float c) {
  return __builtin_amdgcn_fdot2(__builtin_bit_cast(h2v, a),
                                __builtin_bit_cast(h2v, b), c, false);
}
#else
__device__ __forceinline__ float fdot2(unsigned int a, unsigned int b, float c) {
  float2 fa = h2f2(a), fb = h2f2(b);
  return fmaf(fa.y, fb.y, fmaf(fa.x, fb.x, c));
}
#endif

// ---------------- K0: LayerNorm stats per (bb, pixel-pair) ----------------
__global__ __launch_bounds__(256) void k_stats(const float2* __restrict__ x2,
                                               float4* __restrict__ stats4) {
  int id = blockIdx.x * 256 + threadIdx.x;   // 32 * 8192
  int bb = id >> 13;
  int jp = id & 8191;
  const float2* xp = x2 + ((size_t)bb << 19) + jp;
  float s0 = 0.f, q0 = 0.f, s1 = 0.f, q1 = 0.f;
#pragma unroll
  for (int ci = 0; ci < 64; ++ci) {
    float2 v = xp[(size_t)ci << 13];
    s0 += v.x; q0 = fmaf(v.x, v.x, q0);
    s1 += v.y; q1 = fmaf(v.y, v.y, q1);
  }
  float mu0 = s0 * (1.f / 64.f), mu1 = s1 * (1.f / 64.f);
  float4 r;
  r.x = mu0; r.y = rsqrtf(fmaf(-mu0, mu0, q0 * (1.f / 64.f)) + 1e-5f);
  r.z = mu1; r.w = rsqrtf(fmaf(-mu1, mu1, q1 * (1.f / 64.f)) + 1e-5f);
  stats4[id] = r;
}

// ---------------- K0b: pack all weights to half2 ----------------
__global__ __launch_bounds__(256) void k_wpack(
    const float* __restrict__ qkvw, const float* __restrict__ dww,
    const float* __restrict__ projw, unsigned int* __restrict__ qkvpk,
    unsigned int* __restrict__ dwpk, unsigned int* __restrict__ projpk) {
  int t = blockIdx.x * 256 + threadIdx.x;
  if (t < 2048) {
    int o = t >> 5, c2 = t & 31;
    projpk[t] = f2h2(projw[(o << 6) + 2 * c2], projw[(o << 6) + 2 * c2 + 1]);
  } else if (t < 2432) {
    int i = t - 2048;
    int ch = i >> 3, tp = i & 7;
    qkvpk[i] = f2h2(qkvw[(ch << 4) + 2 * tp], qkvw[(ch << 4) + 2 * tp + 1]);
  } else if (t < 2648) {
    int i = t - 2432;
    int pl = i / 9, k = i - pl * 9;
    dwpk[i] = f2h2(dww[18 * pl + k], dww[18 * pl + 9 + k]);
  }
}

// ---------------- K1: fused LN + MFMA 1x1 + dw3x3 + attn partials + v -----
// grid (64 = 4 tx * 16 ty tiles of 32x8 px, 128 = bt*64+ci), block 256.
// Halo 36 cols (34 valid) x 10 rows = 360 positions, padded to 368.
__global__ __launch_bounds__(256) void k_fused(
    const float* __restrict__ x, const float2* __restrict__ stats2,
    const float* __restrict__ lnw, const float* __restrict__ lnb,
    const unsigned int* __restrict__ qkvpk, const unsigned int* __restrict__ dwpk,
    unsigned int* __restrict__ vbuf, float* __restrict__ Sacc,
    float* __restrict__ Nacc) {
  __shared__ unsigned int xnl[2944];   // 2 kg-subarrays x 368 pos x 4 words
  __shared__ unsigned int pre[2976];   // 8 planes x 372 (stride pad)
  __shared__ unsigned int qk[2080];    // 16 ch rows x 130 px-pair words
  int tid = threadIdx.x;
  int bc = blockIdx.y, bt = bc >> 6, ci = bc & 63;
  int tx0 = (blockIdx.x & 3) << 5;
  int ty0 = (blockIdx.x >> 2) << 3;
  float lw = lnw[ci], lb = lnb[ci];

  // ---- Phase 0: LN'd x (fp16 t-pair words) -> xn LDS tile ----
  {
    size_t xci = ((size_t)(bt * 1024 + ci)) << 14;
    int sb = bt << 18;   // (bt*16)<<14
#pragma unroll
    for (int it = 0; it < 2; ++it) {
      int pos = tid + (it << 8);
      if (pos < 360) {
        int hy = pos / 36, hx = pos - hy * 36;
        int gy = ty0 + hy - 1, gx = tx0 + hx - 1;
        bool ok = (hx < 34) && ((unsigned)gy < 128u) && ((unsigned)gx < 128u);
        int gp = (gy << 7) + gx;
        unsigned int w[8];
#pragma unroll
        for (int tp = 0; tp < 8; ++tp) {
          unsigned int ww = 0;
          if (ok) {
            float x0 = x[xci + ((size_t)(2 * tp) << 20) + gp];
            float x1 = x[xci + ((size_t)(2 * tp + 1) << 20) + gp];
            float2 s0 = stats2[sb + ((2 * tp) << 14) + gp];
            float2 s1 = stats2[sb + ((2 * tp + 1) << 14) + gp];
            ww = f2h2(fmaf((x0 - s0.x) * s0.y, lw, lb),
                      fmaf((x1 - s1.x) * s1.y, lw, lb));
          }
          w[tp] = ww;
        }
        *reinterpret_cast<uint4*>(&xnl[pos * 4]) = make_uint4(w[0], w[1], w[2], w[3]);
        *reinterpret_cast<uint4*>(&xnl[1472 + pos * 4]) =
            make_uint4(w[4], w[5], w[6], w[7]);
      }
    }
  }
  __syncthreads();

  int lane15 = tid & 15;
  int kg = (tid >> 4) & 3;
  int wv = tid >> 6;
  int jx = tid & 7, iy = (tid >> 3) & 7, pq = wv;

  for (int m = 0; m < 3; ++m) {
    // ---- S/N partials for previous chunk (reads qk; concurrent w/ MFMA) ----
    if (m > 0) {
      int pm = m - 1;
      {
        int combo = tid >> 3, pc = tid & 7;
        int hp_ = combo >> 4, cd = combo & 15, cc = cd >> 2, dd = cd & 3;
        const unsigned int* qrow = qk + (4 * hp_ + cc) * 130;
        const unsigned int* krow = qk + (8 + 4 * hp_ + dd) * 130;
        float s = 0.f;
#pragma unroll
        for (int i = 0; i < 8; ++i) {
          uint2 q2 = *reinterpret_cast<const uint2*>(&qrow[2 * pc + (i << 4)]);
          uint2 k2 = *reinterpret_cast<const uint2*>(&krow[2 * pc + (i << 4)]);
          s = fdot2(q2.x, k2.x, s);
          s = fdot2(q2.y, k2.y, s);
        }
        s += __shfl_xor(s, 1); s += __shfl_xor(s, 2); s += __shfl_xor(s, 4);
        if (pc == 0)
          atomicAdd(&Sacc[((bc << 2) + 2 * pm + hp_) * 16 + cc * 4 + dd], s);
      }
      {
        int row = tid >> 4, pc = tid & 15;
        const unsigned int* rp = qk + row * 130;
        float n = 0.f;
#pragma unroll
        for (int i = 0; i < 4; ++i) {
          uint2 v2 = *reinterpret_cast<const uint2*>(&rp[2 * pc + (i << 5)]);
          n = fdot2(v2.x, v2.x, n);
          n = fdot2(v2.y, v2.y, n);
        }
        n += __shfl_xor(n, 1); n += __shfl_xor(n, 2);
        n += __shfl_xor(n, 4); n += __shfl_xor(n, 8);
        if (pc == 0) {
          int g = (row < 8) ? (8 * pm + row) : (16 + 8 * pm + (row - 8));
          atomicAdd(&Nacc[(bc << 5) + g], n);
        }
      }
    }
    // ---- MFMA 1x1: 16 ch x halo px, K=16 zero-padded to 32 ----
    {
      int gch = (m < 2)
                    ? ((lane15 < 8) ? (8 * m + lane15) : (16 + 8 * m + (lane15 - 8)))
                    : (32 + lane15);
      uint4 aw = make_uint4(0, 0, 0, 0);
      if (kg < 2) aw = *reinterpret_cast<const uint4*>(&qkvpk[gch * 8 + 4 * kg]);
      half8_t af = __builtin_bit_cast(half8_t, aw);
      float4_t zz = {0.f, 0.f, 0.f, 0.f};
      for (int T = wv; T < 23; T += 4) {
        int hp = T * 16 + lane15;
        uint4 bw = make_uint4(0, 0, 0, 0);
        if (kg < 2)
          bw = *reinterpret_cast<const uint4*>(&xnl[kg * 1472 + hp * 4]);
        half8_t bf = __builtin_bit_cast(half8_t, bw);
        float4_t d = __builtin_amdgcn_mfma_f32_16x16x32_f16(af, bf, zz, 0, 0, 0);
        pre[(2 * kg) * 372 + hp] = f2h2(d[0], d[1]);
        pre[(2 * kg + 1) * 372 + hp] = f2h2(d[2], d[3]);
      }
    }
    __syncthreads();
    // ---- dw 3x3: 2 planes/thread, 4 px/thread (b128+b64 reads) ----
#pragma unroll
    for (int p2 = 0; p2 < 2; ++p2) {
      int pl = pq + 4 * p2;
      int gpl = (m < 2) ? ((pl < 4) ? (4 * m + pl) : (8 + 4 * m + (pl - 4)))
                        : (16 + pl);
      const unsigned int* wp = dwpk + gpl * 9;
      __half2 a0 = __floats2half2_rn(0.f, 0.f), a1 = a0, a2 = a0, a3 = a0;
      int base = pl * 372 + iy * 36 + 4 * jx;
#pragma unroll
      for (int dy = 0; dy < 3; ++dy) {
        uint4 C0 = *reinterpret_cast<const uint4*>(&pre[base + dy * 36]);
        uint2 C1 = *reinterpret_cast<const uint2*>(&pre[base + dy * 36 + 4]);
        __half2 c0 = __builtin_bit_cast(__half2, C0.x);
        __half2 c1 = __builtin_bit_cast(__half2, C0.y);
        __half2 c2 = __builtin_bit_cast(__half2, C0.z);
        __half2 c3 = __builtin_bit_cast(__half2, C0.w);
        __half2 c4 = __builtin_bit_cast(__half2, C1.x);
        __half2 c5 = __builtin_bit_cast(__half2, C1.y);
        __half2 w0 = __builtin_bit_cast(__half2, wp[dy * 3 + 0]);
        __half2 w1 = __builtin_bit_cast(__half2, wp[dy * 3 + 1]);
        __half2 w2 = __builtin_bit_cast(__half2, wp[dy * 3 + 2]);
        a0 = __hfma2(w0, c0, a0); a0 = __hfma2(w1, c1, a0); a0 = __hfma2(w2, c2, a0);
        a1 = __hfma2(w0, c1, a1); a1 = __hfma2(w1, c2, a1); a1 = __hfma2(w2, c3, a1);
        a2 = __hfma2(w0, c2, a2); a2 = __hfma2(w1, c3, a2); a2 = __hfma2(w2, c4, a2);
        a3 = __hfma2(w0, c3, a3); a3 = __hfma2(w1, c4, a3); a3 = __hfma2(w2, c5, a3);
      }
      unsigned int u0 = __builtin_bit_cast(unsigned int, a0);
      unsigned int u1 = __builtin_bit_cast(unsigned int, a1);
      unsigned int u2 = __builtin_bit_cast(unsigned int, a2);
      unsigned int u3 = __builtin_bit_cast(unsigned int, a3);
      if (m < 2) {
        uint2 E, O;
        E.x = (u0 & 0xFFFFu) | (u1 << 16);
        E.y = (u2 & 0xFFFFu) | (u3 << 16);
        O.x = (u0 >> 16) | (u1 & 0xFFFF0000u);
        O.y = (u2 >> 16) | (u3 & 0xFFFF0000u);
        int pp = iy * 16 + 2 * jx;
        *reinterpret_cast<uint2*>(&qk[(2 * pl) * 130 + pp]) = E;
        *reinterpret_cast<uint2*>(&qk[(2 * pl + 1) * 130 + pp]) = O;
      } else {
        size_t idx = ((size_t)(bc * 8 + pl) << 14) +
                     (size_t)((ty0 + iy) << 7) + tx0 + 4 * jx;
        *reinterpret_cast<uint4*>(&vbuf[idx]) = make_uint4(u0, u1, u2, u3);
      }
    }
    if (m < 2) __syncthreads();   // qk visible to next chunk's S/N; pre reuse
  }
}

// ---------------- K2: softmax -> packed fp16 attention rows ----------------
__global__ __launch_bounds__(256) void k_softmax(
    const float* __restrict__ Sacc, const float* __restrict__ Nacc,
    const float* __restrict__ temp, unsigned int* __restrict__ attnpk) {
  int idx = blockIdx.x * 256 + threadIdx.x;
  if (idx >= 512) return;
  int b = idx >> 2, hd = idx & 3;   // b = bt*64 + ci
  int bt = b >> 6, ci = b & 63;
  float tp = temp[hd];
  float iq[4], ik[4];
#pragma unroll
  for (int c = 0; c < 4; ++c) {
    iq[c] = 1.f / fmaxf(sqrtf(Nacc[(b << 5) + (hd << 2) + c]), 1e-12f);
    ik[c] = 1.f / fmaxf(sqrtf(Nacc[(b << 5) + 16 + (hd << 2) + c]), 1e-12f);
  }
  const float* Sp = Sacc + ((b << 2) + hd) * 16;
#pragma unroll
  for (int c = 0; c < 4; ++c) {
    float l[4];
#pragma unroll
    for (int d = 0; d < 4; ++d) l[d] = Sp[c * 4 + d] * iq[c] * ik[d] * tp;
    float m = fmaxf(fmaxf(l[0], l[1]), fmaxf(l[2], l[3]));
    float e0 = expf(l[0] - m), e1 = expf(l[1] - m);
    float e2 = expf(l[2] - m), e3 = expf(l[3] - m);
    float inv = 1.f / (e0 + e1 + e2 + e3);
    unsigned int* dst = attnpk + ((((bt * 4 + hd) * 4 + c) << 7) + ci * 2);
    dst[0] = f2h2(e0 * inv, e1 * inv);
    dst[1] = f2h2(e2 * inv, e3 * inv);
  }
}

// ---------------- K3: out = proj @ (attn . v) via MFMA ----------------
// grid (64 px-blocks of 256, 32 = bt*16 + hd*4 + c), block 256.
__global__ __launch_bounds__(256) void k_outproj(
    const unsigned int* __restrict__ vbuf, const unsigned int* __restrict__ attnpk,
    const unsigned int* __restrict__ projpk, float* __restrict__ out) {
  __shared__ unsigned int Yl[32 * 260];   // [ci2][px], stride 260
  __shared__ unsigned int attn_l[128];
  int tid = threadIdx.x;
  int comb = blockIdx.y;
  int bt = comb >> 4, hd = (comb >> 2) & 3;
  int lane15 = tid & 15;
  int kg = (tid >> 4) & 3;
  int wv = tid >> 6;

  if (tid < 128)
    attn_l[tid] = attnpk[((((bt << 2) + hd) * 4 + (comb & 3)) << 7) + tid];
  __syncthreads();

  // ---- stage Y[ci][px] = sum_d attn[d] v[d][px] (fp16 pairs) ----
  {
    int gpx = (blockIdx.x << 8) + tid;
    size_t vb = (((size_t)bt * 512 + hd * 2) << 14) + gpx;
#pragma unroll
    for (int ci2 = 0; ci2 < 32; ++ci2) {
      size_t b0 = vb + (((size_t)(2 * ci2) * 8) << 14);
      size_t b1 = b0 + ((size_t)8 << 14);
      unsigned int va0 = vbuf[b0], vb0 = vbuf[b0 + 16384];
      unsigned int va1 = vbuf[b1], vb1 = vbuf[b1 + 16384];
      uint4 aw = *reinterpret_cast<const uint4*>(&attn_l[4 * ci2]);
      float y0 = fdot2(va0, aw.x, fdot2(vb0, aw.y, 0.f));
      float y1 = fdot2(va1, aw.z, fdot2(vb1, aw.w, 0.f));
      Yl[ci2 * 260 + tid] = f2h2(y0, y1);
    }
  }
  __syncthreads();

  // ---- MFMA: out[64 o][256 px] = proj(64x64) @ Y(64x256) ----
  half8_t A0[4], A1[4];
#pragma unroll
  for (int ot = 0; ot < 4; ++ot) {
    A0[ot] = __builtin_bit_cast(
        half8_t, *reinterpret_cast<const uint4*>(
                     &projpk[(ot * 16 + lane15) * 32 + kg * 4]));
    A1[ot] = __builtin_bit_cast(
        half8_t, *reinterpret_cast<const uint4*>(
                     &projpk[(ot * 16 + lane15) * 32 + 16 + kg * 4]));
  }
  float4_t zz = {0.f, 0.f, 0.f, 0.f};
  size_t outbase = ((size_t)comb << 20) + (blockIdx.x << 8);
#pragma unroll
  for (int pt = 0; pt < 4; ++pt) {
    int pxl = wv * 64 + pt * 16 + lane15;
    // B: Y rows kg*4..+3 (ci 8kg..8kg+7) and +16 at column pxl
    unsigned int r0 = Yl[(kg * 4 + 0) * 260 + pxl];
    unsigned int r1 = Yl[(kg * 4 + 1) * 260 + pxl];
    unsigned int r2 = Yl[(kg * 4 + 2) * 260 + pxl];
    unsigned int r3 = Yl[(kg * 4 + 3) * 260 + pxl];
    half8_t B0 = __builtin_bit_cast(half8_t, make_uint4(r0, r1, r2, r3));
    unsigned int s0 = Yl[(16 + kg * 4 + 0) * 260 + pxl];
    unsigned int s1 = Yl[(16 + kg * 4 + 1) * 260 + pxl];
    unsigned int s2 = Yl[(16 + kg * 4 + 2) * 260 + pxl];
    unsigned int s3 = Yl[(16 + kg * 4 + 3) * 260 + pxl];
    half8_t B1 = __builtin_bit_cast(half8_t, make_uint4(s0, s1, s2, s3));
#pragma unroll
    for (int ot = 0; ot < 4; ++ot) {
      float4_t d = __builtin_amdgcn_mfma_f32_16x16x32_f16(A0[ot], B0, zz, 0, 0, 0);
      d = __builtin_amdgcn_mfma_f32_16x16x32_f16(A1[ot], B1, d, 0, 0, 0);
      int o0 = ot * 16 + kg * 4;
#pragma unroll
      for (int r = 0; r < 4; ++r)
        out[outbase + ((size_t)(o0 + r) << 14) + pxl] = d[r];
    }
  }
}

extern "C" void kernel_launch(void* const* d_in, const int* in_sizes, int n_in,
                              void* d_out, int out_size, void* d_ws, size_t ws_size,
                              hipStream_t stream) {
  const float* x = (const float*)d_in[0];
  const float* lnw = (const float*)d_in[1];
  const float* lnb = (const float*)d_in[2];
  const float* qkvw = (const float*)d_in[3];
  const float* dww = (const float*)d_in[4];
  const float* projw = (const float*)d_in[5];
  const float* temp = (const float*)d_in[6];
  float* out = (float*)d_out;

  // workspace: vbuf 64 MiB | stats 4 MiB | Sacc | Nacc | attnpk | projpk |
  //            qkvpk | dwpk  (~68.1 MiB total)
  unsigned int* vbuf = (unsigned int*)d_ws;
  char* tail = (char*)d_ws + 67108864ull;
  float4* stats4 = (float4*)tail;                         // 4 MiB
  float* Sacc = (float*)(tail + 4194304ull);              // 8192 f32
  float* Nacc = Sacc + 8192;                              // 4096 f32
  unsigned int* attnpk = (unsigned int*)(Nacc + 4096);    // 4096 u32
  unsigned int* projpk = attnpk + 4096;                   // 2048 u32
  unsigned int* qkvpk = projpk + 2048;                    // 384 u32
  unsigned int* dwpk = qkvpk + 384;                       // 216 u32

  hipMemsetAsync(Sacc, 0, (8192 + 4096) * sizeof(float), stream);
  k_stats<<<dim3(1024), dim3(256), 0, stream>>>((const float2*)x, stats4);
  k_wpack<<<dim3(11), dim3(256), 0, stream>>>(qkvw, dww, projw, qkvpk, dwpk, projpk);
  k_fused<<<dim3(64, 128), dim3(256), 0, stream>>>(
      x, (const float2*)stats4, lnw, lnb, qkvpk, dwpk, vbuf, Sacc, Nacc);
  k_softmax<<<dim3(2), dim3(256), 0, stream>>>(Sacc, Nacc, temp, attnpk);
  k_outproj<<<dim3(64, 32), dim3(256), 0, stream>>>(vbuf, attnpk, projpk, out);
}

// Round 11
// 200.717 us; speedup vs baseline: 1.1704x; 1.0706x over previous
//
#include <hip/hip_runtime.h>
#include <hip/hip_fp16.h>

typedef _Float16 half8_t __attribute__((ext_vector_type(8)));
typedef float float4_t __attribute__((ext_vector_type(4)));

__device__ __forceinline__ float2 h2f2(unsigned int u) {
  return __half22float2(__builtin_bit_cast(__half2, u));
}
__device__ __forceinline__ unsigned int f2h2(float a, float b) {
  return __builtin_bit_cast(unsigned int, __floats2half2_rn(a, b));
}

#if __has_builtin(__builtin_amdgcn_fdot2)
typedef _Float16 h2v __attribute__((ext_vector_type(2)));
__device__ __forceinline__ float fdot2(unsigned int a, unsigned int b, float c) {
  return __builtin_amdgcn_fdot2(__builtin_bit_cast(h2v, a),
                                __builtin_bit_cast(h2v, b), c, false);
}
#else
__device__ __forceinline__ float fdot2(unsigned int a, unsigned int b, float c) {
  float2 fa = h2f2(a), fb = h2f2(b);
  return fmaf(fa.y, fb.y, fmaf(fa.x, fb.x, c));
}
#endif

// ---------------- K0: LN stats (blocks 0..1023) + weight pack (block 1024) --
__global__ __launch_bounds__(256) void k_stats(
    const float2* __restrict__ x2, float4* __restrict__ stats4,
    const float* __restrict__ qkvw, const float* __restrict__ dww,
    const float* __restrict__ projw, unsigned int* __restrict__ qkvpk,
    unsigned int* __restrict__ dwpk, unsigned int* __restrict__ projpk) {
  if (blockIdx.x >= 1024) {
    for (int t = threadIdx.x; t < 2648; t += 256) {
      if (t < 2048) {
        int o = t >> 5, c2 = t & 31;
        projpk[t] = f2h2(projw[(o << 6) + 2 * c2], projw[(o << 6) + 2 * c2 + 1]);
      } else if (t < 2432) {
        int i = t - 2048;
        int ch = i >> 3, tp = i & 7;
        qkvpk[i] = f2h2(qkvw[(ch << 4) + 2 * tp], qkvw[(ch << 4) + 2 * tp + 1]);
      } else {
        int i = t - 2432;
        int pl = i / 9, k = i - pl * 9;
        dwpk[i] = f2h2(dww[18 * pl + k], dww[18 * pl + 9 + k]);
      }
    }
    return;
  }
  int id = blockIdx.x * 256 + threadIdx.x;   // 32 * 8192
  int bb = id >> 13;
  int jp = id & 8191;
  const float2* xp = x2 + ((size_t)bb << 19) + jp;
  float s0 = 0.f, q0 = 0.f, s1 = 0.f, q1 = 0.f;
#pragma unroll
  for (int ci = 0; ci < 64; ++ci) {
    float2 v = xp[(size_t)ci << 13];
    s0 += v.x; q0 = fmaf(v.x, v.x, q0);
    s1 += v.y; q1 = fmaf(v.y, v.y, q1);
  }
  float mu0 = s0 * (1.f / 64.f), mu1 = s1 * (1.f / 64.f);
  float4 r;
  r.x = mu0; r.y = rsqrtf(fmaf(-mu0, mu0, q0 * (1.f / 64.f)) + 1e-5f);
  r.z = mu1; r.w = rsqrtf(fmaf(-mu1, mu1, q1 * (1.f / 64.f)) + 1e-5f);
  stats4[id] = r;
}

// ---------------- K1: fused LN + MFMA 1x1 + dw3x3 + attn partials + v -----
// grid (64 = 4 tx * 16 ty tiles of 32x8 px, 128 = bt*64+ci), block 256.
// Halo window even-aligned: col h=0 <-> gx = tx0-2; 36 cols x 10 rows.
__global__ __launch_bounds__(256) void k_fused(
    const float* __restrict__ x, const float4* __restrict__ stats4,
    const float* __restrict__ lnw, const float* __restrict__ lnb,
    const unsigned int* __restrict__ qkvpk, const unsigned int* __restrict__ dwpk,
    unsigned int* __restrict__ vbuf, float* __restrict__ Sacc,
    float* __restrict__ Nacc) {
  __shared__ unsigned int xnl[2944];   // 2 kg-planes x 368 pos x 4 words
  __shared__ unsigned int pre[2976];   // 8 planes x 372
  __shared__ unsigned int qk[2080];    // 16 ch rows x 130 px-pair words
  int tid = threadIdx.x;
  int bc = blockIdx.y, bt = bc >> 6, ci = bc & 63;
  int tx0 = (blockIdx.x & 3) << 5;
  int ty0 = (blockIdx.x >> 2) << 3;
  float lw = lnw[ci], lb = lnb[ci];

  // ---- Phase 0: pair-task staging (180 tasks), vector loads ----
  if (tid < 180) {
    int hy = tid / 18, hpx = tid - hy * 18;
    int gy = ty0 + hy - 1;
    int gx = tx0 - 2 + 2 * hpx;   // even
    bool ok = ((unsigned)gy < 128u) && ((unsigned)gx < 127u);
    unsigned int w0[8], w1[8];
#pragma unroll
    for (int tp = 0; tp < 8; ++tp) { w0[tp] = 0; w1[tp] = 0; }
    if (ok) {
      size_t xci = ((size_t)(bt * 1024 + ci) << 14) + (gy << 7) + gx;
      int jp = (gy << 6) + (gx >> 1);
#pragma unroll
      for (int tp = 0; tp < 8; ++tp) {
        float2 xa = *reinterpret_cast<const float2*>(&x[xci + ((size_t)(2 * tp) << 20)]);
        float2 xb = *reinterpret_cast<const float2*>(&x[xci + ((size_t)(2 * tp + 1) << 20)]);
        float4 sa = stats4[((size_t)((bt << 4) + 2 * tp) << 13) + jp];
        float4 sb = stats4[((size_t)((bt << 4) + 2 * tp + 1) << 13) + jp];
        w0[tp] = f2h2(fmaf((xa.x - sa.x) * sa.y, lw, lb),
                      fmaf((xb.x - sb.x) * sb.y, lw, lb));   // px0: (t,t+1)
        w1[tp] = f2h2(fmaf((xa.y - sa.z) * sa.w, lw, lb),
                      fmaf((xb.y - sb.z) * sb.w, lw, lb));   // px1
      }
    }
    int pos = hy * 36 + 2 * hpx;
    *reinterpret_cast<uint4*>(&xnl[pos * 4]) = make_uint4(w0[0], w0[1], w0[2], w0[3]);
    *reinterpret_cast<uint4*>(&xnl[(pos + 1) * 4]) =
        make_uint4(w1[0], w1[1], w1[2], w1[3]);
    *reinterpret_cast<uint4*>(&xnl[1472 + pos * 4]) =
        make_uint4(w0[4], w0[5], w0[6], w0[7]);
    *reinterpret_cast<uint4*>(&xnl[1472 + (pos + 1) * 4]) =
        make_uint4(w1[4], w1[5], w1[6], w1[7]);
  }
  __syncthreads();

  int lane15 = tid & 15;
  int kg = (tid >> 4) & 3;
  int wv = tid >> 6;
  int jx = tid & 7, iy = (tid >> 3) & 7, pq = wv;

  for (int m = 0; m < 3; ++m) {
    // ---- S/N partials for previous chunk (reads qk) ----
    if (m > 0) {
      int pm = m - 1;
      {
        int combo = tid >> 3, pc = tid & 7;
        int hp_ = combo >> 4, cd = combo & 15, cc = cd >> 2, dd = cd & 3;
        const unsigned int* qrow = qk + (4 * hp_ + cc) * 130;
        const unsigned int* krow = qk + (8 + 4 * hp_ + dd) * 130;
        float s = 0.f;
#pragma unroll
        for (int i = 0; i < 8; ++i) {
          uint2 q2 = *reinterpret_cast<const uint2*>(&qrow[2 * pc + (i << 4)]);
          uint2 k2 = *reinterpret_cast<const uint2*>(&krow[2 * pc + (i << 4)]);
          s = fdot2(q2.x, k2.x, s);
          s = fdot2(q2.y, k2.y, s);
        }
        s += __shfl_xor(s, 1); s += __shfl_xor(s, 2); s += __shfl_xor(s, 4);
        if (pc == 0)
          atomicAdd(&Sacc[((bc << 2) + 2 * pm + hp_) * 16 + cc * 4 + dd], s);
      }
      {
        int row = tid >> 4, pc = tid & 15;
        const unsigned int* rp = qk + row * 130;
        float n = 0.f;
#pragma unroll
        for (int i = 0; i < 4; ++i) {
          uint2 v2 = *reinterpret_cast<const uint2*>(&rp[2 * pc + (i << 5)]);
          n = fdot2(v2.x, v2.x, n);
          n = fdot2(v2.y, v2.y, n);
        }
        n += __shfl_xor(n, 1); n += __shfl_xor(n, 2);
        n += __shfl_xor(n, 4); n += __shfl_xor(n, 8);
        if (pc == 0) {
          int g = (row < 8) ? (8 * pm + row) : (16 + 8 * pm + (row - 8));
          atomicAdd(&Nacc[(bc << 5) + g], n);
        }
      }
    }
    // ---- MFMA 1x1: 16 ch x halo pos, K=16 zero-padded to 32 ----
    {
      int gch = (m < 2)
                    ? ((lane15 < 8) ? (8 * m + lane15) : (16 + 8 * m + (lane15 - 8)))
                    : (32 + lane15);
      uint4 aw = make_uint4(0, 0, 0, 0);
      if (kg < 2) aw = *reinterpret_cast<const uint4*>(&qkvpk[gch * 8 + 4 * kg]);
      half8_t af = __builtin_bit_cast(half8_t, aw);
      float4_t zz = {0.f, 0.f, 0.f, 0.f};
      for (int T = wv; T < 23; T += 4) {
        int hp = T * 16 + lane15;
        uint4 bw = make_uint4(0, 0, 0, 0);
        if (kg < 2)
          bw = *reinterpret_cast<const uint4*>(&xnl[kg * 1472 + hp * 4]);
        half8_t bf = __builtin_bit_cast(half8_t, bw);
        float4_t d = __builtin_amdgcn_mfma_f32_16x16x32_f16(af, bf, zz, 0, 0, 0);
        pre[(2 * kg) * 372 + hp] = f2h2(d[0], d[1]);
        pre[(2 * kg + 1) * 372 + hp] = f2h2(d[2], d[3]);
      }
    }
    __syncthreads();
    // ---- dw 3x3: 2 planes/thread, 4 px/thread; taps at word X+dx+1 ----
#pragma unroll
    for (int p2 = 0; p2 < 2; ++p2) {
      int pl = pq + 4 * p2;
      int gpl = (m < 2) ? ((pl < 4) ? (4 * m + pl) : (8 + 4 * m + (pl - 4)))
                        : (16 + pl);
      const unsigned int* wp = dwpk + gpl * 9;
      __half2 a0 = __floats2half2_rn(0.f, 0.f), a1 = a0, a2 = a0, a3 = a0;
      int base = pl * 372 + iy * 36 + 4 * jx;
#pragma unroll
      for (int dy = 0; dy < 3; ++dy) {
        uint4 C0 = *reinterpret_cast<const uint4*>(&pre[base + dy * 36]);
        uint4 C1 = *reinterpret_cast<const uint4*>(&pre[base + dy * 36 + 4]);
        __half2 c1 = __builtin_bit_cast(__half2, C0.y);
        __half2 c2 = __builtin_bit_cast(__half2, C0.z);
        __half2 c3 = __builtin_bit_cast(__half2, C0.w);
        __half2 c4 = __builtin_bit_cast(__half2, C1.x);
        __half2 c5 = __builtin_bit_cast(__half2, C1.y);
        __half2 c6 = __builtin_bit_cast(__half2, C1.z);
        __half2 w0 = __builtin_bit_cast(__half2, wp[dy * 3 + 0]);
        __half2 w1 = __builtin_bit_cast(__half2, wp[dy * 3 + 1]);
        __half2 w2 = __builtin_bit_cast(__half2, wp[dy * 3 + 2]);
        a0 = __hfma2(w0, c1, a0); a0 = __hfma2(w1, c2, a0); a0 = __hfma2(w2, c3, a0);
        a1 = __hfma2(w0, c2, a1); a1 = __hfma2(w1, c3, a1); a1 = __hfma2(w2, c4, a1);
        a2 = __hfma2(w0, c3, a2); a2 = __hfma2(w1, c4, a2); a2 = __hfma2(w2, c5, a2);
        a3 = __hfma2(w0, c4, a3); a3 = __hfma2(w1, c5, a3); a3 = __hfma2(w2, c6, a3);
      }
      unsigned int u0 = __builtin_bit_cast(unsigned int, a0);
      unsigned int u1 = __builtin_bit_cast(unsigned int, a1);
      unsigned int u2 = __builtin_bit_cast(unsigned int, a2);
      unsigned int u3 = __builtin_bit_cast(unsigned int, a3);
      if (m < 2) {
        uint2 E, O;
        E.x = (u0 & 0xFFFFu) | (u1 << 16);
        E.y = (u2 & 0xFFFFu) | (u3 << 16);
        O.x = (u0 >> 16) | (u1 & 0xFFFF0000u);
        O.y = (u2 >> 16) | (u3 & 0xFFFF0000u);
        int pp = iy * 16 + 2 * jx;
        *reinterpret_cast<uint2*>(&qk[(2 * pl) * 130 + pp]) = E;
        *reinterpret_cast<uint2*>(&qk[(2 * pl + 1) * 130 + pp]) = O;
      } else {
        size_t idx = ((size_t)(bc * 8 + pl) << 14) +
                     (size_t)((ty0 + iy) << 7) + tx0 + 4 * jx;
        *reinterpret_cast<uint4*>(&vbuf[idx]) = make_uint4(u0, u1, u2, u3);
      }
    }
    if (m < 2) __syncthreads();
  }
}

// ---------------- K2: softmax (in-block) + out = proj @ (attn . v) MFMA ---
// grid (64 px-blocks of 256, 32 = bt*16 + hd*4 + c), block 256.
__global__ __launch_bounds__(256) void k_outproj(
    const unsigned int* __restrict__ vbuf, const float* __restrict__ Sacc,
    const float* __restrict__ Nacc, const float* __restrict__ temp,
    const unsigned int* __restrict__ projpk, float* __restrict__ out) {
  __shared__ unsigned int Yl[32 * 260];   // [ci2][px], stride 260
  __shared__ unsigned int attn_l[128];
  int tid = threadIdx.x;
  int comb = blockIdx.y;
  int bt = comb >> 4, hd = (comb >> 2) & 3, c = comb & 3;
  int lane15 = tid & 15;
  int kg = (tid >> 4) & 3;
  int wv = tid >> 6;

  if (tid < 64) {   // per-ci softmax row (c fixed per block)
    int b = (bt << 6) + tid;
    float tp = temp[hd];
    float iq = 1.f / fmaxf(sqrtf(Nacc[(b << 5) + (hd << 2) + c]), 1e-12f);
    float l[4];
#pragma unroll
    for (int d = 0; d < 4; ++d) {
      float ik = 1.f / fmaxf(sqrtf(Nacc[(b << 5) + 16 + (hd << 2) + d]), 1e-12f);
      l[d] = Sacc[((b << 2) + hd) * 16 + c * 4 + d] * iq * ik * tp;
    }
    float mx = fmaxf(fmaxf(l[0], l[1]), fmaxf(l[2], l[3]));
    float e0 = expf(l[0] - mx), e1 = expf(l[1] - mx);
    float e2 = expf(l[2] - mx), e3 = expf(l[3] - mx);
    float inv = 1.f / (e0 + e1 + e2 + e3);
    attn_l[2 * tid] = f2h2(e0 * inv, e1 * inv);
    attn_l[2 * tid + 1] = f2h2(e2 * inv, e3 * inv);
  }
  __syncthreads();

  // ---- stage Y[ci][px] = sum_d attn[d] v[d][px] (fp16 pairs) ----
  {
    int gpx = (blockIdx.x << 8) + tid;
    size_t vb = (((size_t)bt * 512 + hd * 2) << 14) + gpx;
#pragma unroll
    for (int ci2 = 0; ci2 < 32; ++ci2) {
      size_t b0 = vb + (((size_t)(2 * ci2) * 8) << 14);
      size_t b1 = b0 + ((size_t)8 << 14);
      unsigned int va0 = vbuf[b0], vb0 = vbuf[b0 + 16384];
      unsigned int va1 = vbuf[b1], vb1 = vbuf[b1 + 16384];
      uint4 aw = *reinterpret_cast<const uint4*>(&attn_l[4 * ci2]);
      float y0 = fdot2(va0, aw.x, fdot2(vb0, aw.y, 0.f));
      float y1 = fdot2(va1, aw.z, fdot2(vb1, aw.w, 0.f));
      Yl[ci2 * 260 + tid] = f2h2(y0, y1);
    }
  }
  __syncthreads();

  // ---- MFMA: out[64 o][256 px] = proj(64x64) @ Y(64x256) ----
  half8_t A0[4], A1[4];
#pragma unroll
  for (int ot = 0; ot < 4; ++ot) {
    A0[ot] = __builtin_bit_cast(
        half8_t, *reinterpret_cast<const uint4*>(
                     &projpk[(ot * 16 + lane15) * 32 + kg * 4]));
    A1[ot] = __builtin_bit_cast(
        half8_t, *reinterpret_cast<const uint4*>(
                     &projpk[(ot * 16 + lane15) * 32 + 16 + kg * 4]));
  }
  float4_t zz = {0.f, 0.f, 0.f, 0.f};
  size_t outbase = ((size_t)comb << 20) + (blockIdx.x << 8);
#pragma unroll
  for (int pt = 0; pt < 4; ++pt) {
    int pxl = wv * 64 + pt * 16 + lane15;
    unsigned int r0 = Yl[(kg * 4 + 0) * 260 + pxl];
    unsigned int r1 = Yl[(kg * 4 + 1) * 260 + pxl];
    unsigned int r2 = Yl[(kg * 4 + 2) * 260 + pxl];
    unsigned int r3 = Yl[(kg * 4 + 3) * 260 + pxl];
    half8_t B0 = __builtin_bit_cast(half8_t, make_uint4(r0, r1, r2, r3));
    unsigned int s0 = Yl[(16 + kg * 4 + 0) * 260 + pxl];
    unsigned int s1 = Yl[(16 + kg * 4 + 1) * 260 + pxl];
    unsigned int s2 = Yl[(16 + kg * 4 + 2) * 260 + pxl];
    unsigned int s3 = Yl[(16 + kg * 4 + 3) * 260 + pxl];
    half8_t B1 = __builtin_bit_cast(half8_t, make_uint4(s0, s1, s2, s3));
#pragma unroll
    for (int ot = 0; ot < 4; ++ot) {
      float4_t d = __builtin_amdgcn_mfma_f32_16x16x32_f16(A0[ot], B0, zz, 0, 0, 0);
      d = __builtin_amdgcn_mfma_f32_16x16x32_f16(A1[ot], B1, d, 0, 0, 0);
      int o0 = ot * 16 + kg * 4;
#pragma unroll
      for (int r = 0; r < 4; ++r)
        out[outbase + ((size_t)(o0 + r) << 14) + pxl] = d[r];
    }
  }
}

extern "C" void kernel_launch(void* const* d_in, const int* in_sizes, int n_in,
                              void* d_out, int out_size, void* d_ws, size_t ws_size,
                              hipStream_t stream) {
  const float* x = (const float*)d_in[0];
  const float* lnw = (const float*)d_in[1];
  const float* lnb = (const float*)d_in[2];
  const float* qkvw = (const float*)d_in[3];
  const float* dww = (const float*)d_in[4];
  const float* projw = (const float*)d_in[5];
  const float* temp = (const float*)d_in[6];
  float* out = (float*)d_out;

  // workspace: vbuf 64 MiB | stats 4 MiB | Sacc | Nacc | projpk | qkvpk | dwpk
  unsigned int* vbuf = (unsigned int*)d_ws;
  char* tail = (char*)d_ws + 67108864ull;
  float4* stats4 = (float4*)tail;                         // 4 MiB
  float* Sacc = (float*)(tail + 4194304ull);              // 8192 f32
  float* Nacc = Sacc + 8192;                              // 4096 f32
  unsigned int* projpk = (unsigned int*)(Nacc + 4096);    // 2048 u32
  unsigned int* qkvpk = projpk + 2048;                    // 384 u32
  unsigned int* dwpk = qkvpk + 384;                       // 216 u32

  hipMemsetAsync(Sacc, 0, (8192 + 4096) * sizeof(float), stream);
  k_stats<<<dim3(1025), dim3(256), 0, stream>>>((const float2*)x, stats4, qkvw,
                                                dww, projw, qkvpk, dwpk, projpk);
  k_fused<<<dim3(64, 128), dim3(256), 0, stream>>>(
      x, stats4, lnw, lnb, qkvpk, dwpk, vbuf, Sacc, Nacc);
  k_outproj<<<dim3(64, 32), dim3(256), 0, stream>>>(vbuf, Sacc, Nacc, temp,
                                                    projpk, out);
}